// Round 14
// baseline (3118.920 us; speedup 1.0000x reference)
//
#include <hip/hip_runtime.h>

typedef __attribute__((ext_vector_type(8))) short bf16x8;
typedef __attribute__((ext_vector_type(4))) float f32x4;

#define T_N 512
#define I_N 512
#define H_N 1024
#define O_N 512
#define NCL 4            // clusters; c = bid&3; 16 batch rows = 4 groups x 4
#define NMEM 16          // members; m = bid>>2; 64 h-cols each
#define NTHR 512
#define COLS_H 64
#define KW 192           // recurrence K-slice per wave (8*192 = 1536)
#define AP_STRIDE 1544   // A-panel row stride (1536 + 8 pad)
#define SLOTDW 2048      // ring slot: 4 rows x 1024 cols bf16 = 2048 dwords
#define CANARY 0xFFFFFFFFu
#define HS_CAP 20000000
#define POLL_CAP 200000

__device__ __forceinline__ unsigned short f2bf(float f) {
  unsigned int u = __float_as_uint(f);
  u += 0x7fffu + ((u >> 16) & 1u);
  return (unsigned short)(u >> 16);
}
__device__ __forceinline__ bf16x8 cvt8f(const float* __restrict__ p) {
  float4 a = *(const float4*)p;
  float4 b = *(const float4*)(p + 4);
  bf16x8 r;
  r[0] = (short)f2bf(a.x); r[1] = (short)f2bf(a.y);
  r[2] = (short)f2bf(a.z); r[3] = (short)f2bf(a.w);
  r[4] = (short)f2bf(b.x); r[5] = (short)f2bf(b.y);
  r[6] = (short)f2bf(b.z); r[7] = (short)f2bf(b.w);
  return r;
}
__device__ __forceinline__ bf16x8 cvt8v(float4 a, float4 b) {
  bf16x8 r;
  r[0] = (short)f2bf(a.x); r[1] = (short)f2bf(a.y);
  r[2] = (short)f2bf(a.z); r[3] = (short)f2bf(a.w);
  r[4] = (short)f2bf(b.x); r[5] = (short)f2bf(b.y);
  r[6] = (short)f2bf(b.z); r[7] = (short)f2bf(b.w);
  return r;
}

// RAW workgroup barrier: orders LDS only; vmem stays IN FLIGHT across it.
__device__ __forceinline__ void barrier_lds() {
  asm volatile("s_waitcnt lgkmcnt(0)" ::: "memory");
  __builtin_amdgcn_s_barrier();
  __builtin_amdgcn_sched_barrier(0);
}

// memory-side coherent channel (bypass L1+L2) — the only HW-proven path
__device__ __forceinline__ void st_sc01(unsigned int* p, unsigned int v) {
  asm volatile("global_store_dword %0, %1, off sc0 sc1" :: "v"(p), "v"(v) : "memory");
}
__device__ __forceinline__ void st_raw32(unsigned int* p, unsigned int v) {
  asm volatile("global_store_dword %0, %1, off" :: "v"(p), "v"(v) : "memory");
}
__device__ __forceinline__ unsigned int ld_sc01(const unsigned int* p) {
  unsigned int r;
  asm volatile("global_load_dword %0, %1, off sc0 sc1\n\ts_waitcnt vmcnt(0)"
               : "=v"(r) : "v"(p) : "memory");
  return r;
}
// tied 32-bit load: dest keeps CANARY until the load COMPLETES (safety net).
__device__ __forceinline__ void ld_sc01_rw(unsigned int* d, const unsigned int* p) {
  asm volatile("global_load_dword %0, %1, off sc0 sc1" : "+v"(*d) : "v"(p) : "memory");
}
__device__ __forceinline__ void ld_sc01_nw(unsigned int* d, const unsigned int* p) {
  asm volatile("global_load_dword %0, %1, off sc0 sc1" : "=v"(*d) : "v"(p) : "memory");
}
__device__ __forceinline__ void ld4_rawf(float4* d, const void* p) {
  asm volatile("global_load_dwordx4 %0, %1, off" : "=v"(*d) : "v"(p) : "memory");
}

// -------- one phase of the 4-group interleaved scan --------
// Group G owns cluster rows [4G,4G+4) = MFMA lane-group G. Sweep issued at
// phase k targets the publish from phase k-1 (group (G+3)&3) and is CHECKED
// at phase k+2 (3 phases of flight ≈ 1.5-1.7us > L). Buffers rotate mod 4:
// issue BISS=B[G], check BCHK=B[(G+2)&3] which stages group (G+1)&3's rows.
// vmcnt ledger: waves 0-3 check at vmcnt(25); waves 4-7 x-stage at vmcnt(2).
#define PHASE(G, BISS, BCHK, XS0, XS1, XI0, XI1)                               \
  {                                                                            \
    const bool iss  = ((G) == 0) ? (t >= 1) : (t <= 510);                      \
    const bool chk  = ((G) == 3) ? (t <= 510) : (t >= 1);                      \
    const int  tp   = ((G) == 0) ? (t - 1) : t;                                \
    const int  tpp  = ((G) == 3) ? (t + 1) : t;                                \
    const bool xiss = ((G) == 3) ? (t <= 509) : (t <= 510);                    \
    const bool xstg = (t <= 510);                                              \
    if (tid < 256) {                                                           \
      if (iss) {                                                               \
        const unsigned int* sb =                                               \
            ringc + ((((G) + 3) & 3) * 4 + (tp & 3)) * SLOTDW + tid;           \
        _Pragma("unroll")                                                      \
        for (int q = 0; q < 8; ++q) {                                          \
          BISS[q] = CANARY;                                                    \
          ld_sc01_rw(&BISS[q], sb + 256 * q);                                  \
        }                                                                      \
      }                                                                        \
    } else if (xiss) {                                                         \
      const int u = tid & 255;                                                 \
      const float* px = x + ((size_t)(tpp + 1) * 64 + b0 + 4 * (((G) + 1) & 3) \
                             + (u >> 6)) * I_N + ((u & 63) << 3);              \
      ld4_rawf(&XI0, px); ld4_rawf(&XI1, px + 4);                              \
    }                                                                          \
    /* ---- MFMA over full 16-row panel ---- */                                \
    {                                                                          \
      f32x4 acc0 = {}, acc1 = {}, acc2 = {}, acc3 = {};                        \
      const int abase = (l & 15) * AP_STRIDE + wv * KW + ((l >> 4) << 3);      \
      _Pragma("unroll")                                                        \
      for (int kst = 0; kst < 6; ++kst) {                                      \
        bf16x8 a = *(const bf16x8*)(Apan + abase + kst * 32);                  \
        acc0 = __builtin_amdgcn_mfma_f32_16x16x32_bf16(a, Bh[kst][0], acc0, 0, 0, 0); \
        acc1 = __builtin_amdgcn_mfma_f32_16x16x32_bf16(a, Bh[kst][1], acc1, 0, 0, 0); \
        acc2 = __builtin_amdgcn_mfma_f32_16x16x32_bf16(a, Bh[kst][2], acc2, 0, 0, 0); \
        acc3 = __builtin_amdgcn_mfma_f32_16x16x32_bf16(a, Bh[kst][3], acc3, 0, 0, 0); \
      }                                                                        \
      if ((l >> 4) == (G)) { /* lane-group G holds rows 4G..4G+3 */            \
        float* rb = Rbuf + wv * 256 + (l & 15) * 4;                            \
        *(f32x4*)(rb +   0) = acc0; *(f32x4*)(rb +  64) = acc1;                \
        *(f32x4*)(rb + 128) = acc2; *(f32x4*)(rb + 192) = acc3;                \
      }                                                                        \
    }                                                                          \
    barrier_lds(); /* S1: partials visible; sweeps/x stay in flight */         \
    if (tid < 256) {                                                           \
      float v = pbv;                                                           \
      _Pragma("unroll")                                                        \
      for (int kk = 0; kk < 8; ++kk) v += Rbuf[kk * 256 + tid];                \
      const float hval = tanhf(v);                                             \
      const unsigned int pk16 = f2bf(hval);                                    \
      const unsigned int oth = (unsigned int)__shfl_xor((int)pk16, 4);         \
      if (!(tid & 4)) {                                                        \
        const unsigned int pk = pk16 | (oth << 16);                            \
        const int dwi = (tid & 3) * 512 + m * 32 + (tid >> 3);                 \
        st_sc01(ringc + ((G) * 4 + (t & 3)) * SLOTDW + dwi, pk);               \
        st_sc01(ringc + ((G) * 4 + ((t + 2) & 3)) * SLOTDW + dwi, CANARY);     \
        st_raw32((unsigned int*)hs +                                           \
                 ((size_t)t * 64 + b0 + 4 * (G) + (tid & 3)) * 512 +           \
                 m * 32 + (tid >> 3), pk);                                     \
      }                                                                        \
      if (t == T_N - 1)                                                        \
        hlast[(size_t)(b0 + 4 * (G) + (tid & 3)) * H_N + cbh + (tid >> 2)] = hval; \
      if (chk) {                                                               \
        asm volatile("s_waitcnt vmcnt(25)" ::: "memory");                      \
        __builtin_amdgcn_sched_barrier(0);                                     \
        bool bad = false;                                                      \
        _Pragma("unroll")                                                      \
        for (int q = 0; q < 8; ++q) bad |= (BCHK[q] == CANARY);                \
        if (bad) { /* miscount/straggler fallback: re-poll (always sound) */   \
          const int ts = ((G) == 3) ? t : (t - 1);                             \
          const unsigned int* sb2 =                                            \
              ringc + ((((G) + 1) & 3) * 4 + (ts & 3)) * SLOTDW + tid;         \
          int itc = 0;                                                         \
          do {                                                                 \
            _Pragma("unroll")                                                  \
            for (int q = 0; q < 8; ++q) ld_sc01_nw(&BCHK[q], sb2 + 256 * q);   \
            asm volatile("s_waitcnt vmcnt(0)" ::: "memory");                   \
            __builtin_amdgcn_sched_barrier(0);                                 \
            bad = false;                                                       \
            _Pragma("unroll")                                                  \
            for (int q = 0; q < 8; ++q) bad |= (BCHK[q] == CANARY);            \
          } while (bad && ++itc < POLL_CAP);                                   \
        }                                                                      \
        _Pragma("unroll")                                                      \
        for (int q = 0; q < 8; ++q)                                            \
          *(unsigned int*)(Apan + (4 * (((G) + 1) & 3) + (q >> 1)) * AP_STRIDE \
                           + ((tid + ((q & 1) << 8)) << 1)) = BCHK[q];         \
      }                                                                        \
    } else if (xstg) {                                                         \
      if (xiss) asm volatile("s_waitcnt vmcnt(2)" ::: "memory");               \
      else      asm volatile("s_waitcnt vmcnt(0)" ::: "memory");               \
      __builtin_amdgcn_sched_barrier(0);                                       \
      const int u = tid & 255;                                                 \
      *(bf16x8*)(Apan + (4 * (G) + (u >> 6)) * AP_STRIDE + H_N + ((u & 63) << 3)) \
          = cvt8v(XS0, XS1);                                                   \
    }                                                                          \
    barrier_lds(); /* S2: panel consistent for next phase */                   \
  }

// 4-group interleaved persistent scan. Grid 64 = 4 clusters x 16 members,
// 512 thr (8 waves). Cluster c: batches [16c,16c+16); member m: h-cols
// [64m,64m+64). Writes hs (bf16 [T][64][H]) + hlast (fp32). FC separate.
__global__ __launch_bounds__(NTHR, 2) void rnn_scan(
    const float* __restrict__ x, const float* __restrict__ hidden,
    const float* __restrict__ Wih, const float* __restrict__ Whh,
    const float* __restrict__ bih, const float* __restrict__ bhh,
    unsigned short* __restrict__ hs, float* __restrict__ hlast,
    unsigned int* __restrict__ ring, unsigned int* __restrict__ flags)
{
  __shared__ __align__(16) unsigned short Apan[16 * AP_STRIDE];  // 49408 B
  __shared__ __align__(16) float Rbuf[8 * 256];                  //  8192 B
  __shared__ char pad_[24576];  // -> 82176 B total: strictly 1 block/CU

  const int tid = threadIdx.x;
  const int l = tid & 63, wv = tid >> 6;
  const int bid = blockIdx.x;
  const int c = bid & 3;
  const int m = bid >> 2;
  const int b0 = c * 16;
  const int cbh = m * COLS_H;
  unsigned int* ringc = ring + (size_t)c * 4 * 4 * SLOTDW;  // [4 grp][4 slot]
  unsigned int* bar = flags + c * 64;
  if (x == nullptr) pad_[0] = 1;  // keep the LDS pad alive (never true)

  // ---- persistent recurrence weights: K=1536 = [Whh | Wih], 64 cols ----
  bf16x8 Bh[6][4];
  {
    const int kb0 = wv * KW + ((l >> 4) << 3);
#pragma unroll
    for (int kst = 0; kst < 6; ++kst) {
      const int k = kb0 + kst * 32;
#pragma unroll
      for (int f = 0; f < 4; ++f) {
        const int col = cbh + f * 16 + (l & 15);
        const float* src = (k < H_N) ? (Whh + (size_t)col * H_N + k)
                                     : (Wih + (size_t)col * I_N + (k - H_N));
        Bh[kst][f] = cvt8f(src);
      }
    }
  }
  const int rcol = (tid < 256) ? (tid >> 2) : 0;
  const float pbv = bih[cbh + rcol] + bhh[cbh + rcol];

  // ---- stage hidden rows 0-15 ----
  {
    int q = tid;
#pragma unroll
    for (int i = 0; i < 4; ++i, q += NTHR) {
      const int row = q >> 7, col8 = (q & 127) << 3;
      *(bf16x8*)(Apan + row * AP_STRIDE + col8) =
          cvt8f(hidden + (size_t)(b0 + row) * H_N + col8);
    }
  }
  // ---- stage x_0 rows 0-15 ----
  {
    int q = tid;
#pragma unroll
    for (int i = 0; i < 2; ++i, q += NTHR) {
      const int row = q >> 6, col8 = (q & 63) << 3;
      *(bf16x8*)(Apan + row * AP_STRIDE + H_N + col8) =
          cvt8f(x + (size_t)(b0 + row) * I_N + col8);
    }
  }
  // ---- canary all 16 slot-regions (own columns) ----
  if (tid < 256 && !(tid & 4)) {
    const int dwi = (tid & 3) * 512 + m * 32 + (tid >> 3);
#pragma unroll
    for (int s = 0; s < 16; ++s) st_sc01(ringc + s * SLOTDW + dwi, CANARY);
  }
  asm volatile("s_waitcnt vmcnt(0)" ::: "memory");
  __syncthreads();
  // ---- member barrier (sc1 flags, capped) ----
  if (tid == 0) st_sc01(&bar[m], 1u);
  if (tid < NMEM) {
    int it = 0;
    while (ld_sc01(&bar[tid]) < 1u && ++it < HS_CAP)
      if (it > 64) __builtin_amdgcn_s_sleep(1);
  }
  // ---- preamble x issue: XA <- x^{G0}_1 (staged at phase G0,t=0) ----
  float4 XA0, XA1, XB0, XB1;
  if (wv >= 4) {
    const int u = tid & 255;
    const float* px = x + ((size_t)64 + b0 + (u >> 6)) * I_N + ((u & 63) << 3);
    ld4_rawf(&XA0, px); ld4_rawf(&XA1, px + 4);
  }
  __syncthreads();  // preamble drain: phase-0 vmcnt ledgers start clean

  unsigned int sw0[8], sw1[8], sw2[8], sw3[8];
  for (int t = 0; t < T_N; ++t) {
    PHASE(0, sw0, sw2, XA0, XA1, XB0, XB1)
    PHASE(1, sw1, sw3, XB0, XB1, XA0, XA1)
    PHASE(2, sw2, sw0, XA0, XA1, XB0, XB1)
    PHASE(3, sw3, sw1, XB0, XB1, XA0, XA1)
  }
}

// FC GEMM: C[m][n] = sum_k hs[m][k]*Wfcb[n][k] + bfc[n]; fp32 out.
__global__ __launch_bounds__(256) void gemm_fc(const unsigned short* __restrict__ A,
                                               const unsigned short* __restrict__ Bt,
                                               const float* __restrict__ bias,
                                               float* __restrict__ C) {
  const int N = O_N, K = H_N;
  const int bm = blockIdx.x >> 2, bn = blockIdx.x & 3;
  const int l = threadIdx.x & 63, w = threadIdx.x >> 6;
  const int wr = w >> 1, wc = w & 1;
  const int row_a = bm * 128 + wr * 64 + (l & 15);
  const int row_b = bn * 128 + wc * 64 + (l & 15);
  const int koff = (l >> 4) * 8;
  f32x4 acc[4][4] = {};
  for (int k = 0; k < K; k += 32) {
    bf16x8 a[4], b[4];
#pragma unroll
    for (int i = 0; i < 4; i++)
      a[i] = *(const bf16x8*)(A + (size_t)(row_a + i * 16) * K + k + koff);
#pragma unroll
    for (int i = 0; i < 4; i++)
      b[i] = *(const bf16x8*)(Bt + (size_t)(row_b + i * 16) * K + k + koff);
#pragma unroll
    for (int i = 0; i < 4; i++)
#pragma unroll
      for (int j = 0; j < 4; j++)
        acc[i][j] = __builtin_amdgcn_mfma_f32_16x16x32_bf16(a[i], b[j], acc[i][j], 0, 0, 0);
  }
  const int orow = bm * 128 + wr * 64 + ((l >> 4) << 2);
  const int ocol = bn * 128 + wc * 64 + (l & 15);
#pragma unroll
  for (int i = 0; i < 4; i++)
#pragma unroll
    for (int j = 0; j < 4; j++) {
      const int r0 = orow + i * 16, c0 = ocol + j * 16;
      const float bv = bias[c0];
#pragma unroll
      for (int r = 0; r < 4; r++)
        C[(size_t)(r0 + r) * N + c0] = acc[i][j][r] + bv;
    }
}

// fp32 -> bf16 convert (for Wfc)
__global__ __launch_bounds__(256) void cvt8(const float* __restrict__ s,
                                            unsigned short* __restrict__ d, long n) {
  long i = ((long)blockIdx.x * blockDim.x + threadIdx.x) * 8;
  if (i < n) *(bf16x8*)(d + i) = cvt8f(s + i);
}

extern "C" void kernel_launch(void* const* d_in, const int* in_sizes, int n_in,
                              void* d_out, int out_size, void* d_ws, size_t ws_size,
                              hipStream_t stream) {
  const float* x   = (const float*)d_in[0];
  const float* hid = (const float*)d_in[1];
  const float* Wih = (const float*)d_in[2];
  const float* Whh = (const float*)d_in[3];
  const float* bih = (const float*)d_in[4];
  const float* bhh = (const float*)d_in[5];
  const float* Wfc = (const float*)d_in[6];
  const float* bfc = (const float*)d_in[7];

  float* out   = (float*)d_out;                      // fp32 [T*B][O]
  float* hlast = out + (size_t)32768 * 512;          // fp32 [B][H]

  unsigned int*   flags = (unsigned int*)d_ws;                       // 4 KB
  unsigned int*   ring  = (unsigned int*)((char*)d_ws + 4096);       // 512 KB
  unsigned short* Wfcb  = (unsigned short*)((char*)d_ws + 4096 + 524288);  // 1 MB
  unsigned short* hsb   = Wfcb + (size_t)512 * 1024;                 // 67.1 MB

  (void)hipMemsetAsync(flags, 0, 4096, stream);
  cvt8<<<256, 256, 0, stream>>>(Wfc, Wfcb, (long)512 * 1024);
  rnn_scan<<<64, NTHR, 0, stream>>>(x, hid, Wih, Whh, bih, bhh, hsb, hlast, ring, flags);
  gemm_fc<<<1024, 256, 0, stream>>>(hsb, Wfcb, bfc, out);
}

// Round 15
// 2672.564 us; speedup vs baseline: 1.1670x; 1.1670x over previous
//
#include <hip/hip_runtime.h>

typedef __attribute__((ext_vector_type(8))) short bf16x8;
typedef __attribute__((ext_vector_type(4))) float f32x4;

#define T_N 512
#define I_N 512
#define H_N 1024
#define O_N 512
#define NCL 4            // clusters; c = bid&3; 16 batch rows = 4 groups x 4
#define NMEM 16          // members; m = bid>>2; 64 h-cols each
#define NTHR 512
#define COLS_H 64
#define KW 192           // recurrence K-slice per wave (8*192 = 1536)
#define AP_STRIDE 1544   // A-panel row stride (1536 + 8 pad)
#define SLOTDW 2048      // ring slot: 4 rows x 512 dword col-pairs
#define CANARY 0xFFFFFFFFu
#define HS_CAP 20000000
#define POLL_CAP 200000

__device__ __forceinline__ unsigned short f2bf(float f) {
  unsigned int u = __float_as_uint(f);
  u += 0x7fffu + ((u >> 16) & 1u);
  return (unsigned short)(u >> 16);
}
__device__ __forceinline__ bf16x8 cvt8f(const float* __restrict__ p) {
  float4 a = *(const float4*)p;
  float4 b = *(const float4*)(p + 4);
  bf16x8 r;
  r[0] = (short)f2bf(a.x); r[1] = (short)f2bf(a.y);
  r[2] = (short)f2bf(a.z); r[3] = (short)f2bf(a.w);
  r[4] = (short)f2bf(b.x); r[5] = (short)f2bf(b.y);
  r[6] = (short)f2bf(b.z); r[7] = (short)f2bf(b.w);
  return r;
}
__device__ __forceinline__ bf16x8 cvt8v(float4 a, float4 b) {
  bf16x8 r;
  r[0] = (short)f2bf(a.x); r[1] = (short)f2bf(a.y);
  r[2] = (short)f2bf(a.z); r[3] = (short)f2bf(a.w);
  r[4] = (short)f2bf(b.x); r[5] = (short)f2bf(b.y);
  r[6] = (short)f2bf(b.z); r[7] = (short)f2bf(b.w);
  return r;
}

// RAW workgroup barrier: orders LDS only; vmem stays IN FLIGHT across it.
__device__ __forceinline__ void barrier_lds() {
  asm volatile("s_waitcnt lgkmcnt(0)" ::: "memory");
  __builtin_amdgcn_s_barrier();
  __builtin_amdgcn_sched_barrier(0);
}

// memory-side coherent channel (bypass L1+L2) — the only HW-proven path
__device__ __forceinline__ void st_sc01(unsigned int* p, unsigned int v) {
  asm volatile("global_store_dword %0, %1, off sc0 sc1" :: "v"(p), "v"(v) : "memory");
}
__device__ __forceinline__ void st_raw32(unsigned int* p, unsigned int v) {
  asm volatile("global_store_dword %0, %1, off" :: "v"(p), "v"(v) : "memory");
}
__device__ __forceinline__ unsigned int ld_sc01(const unsigned int* p) {
  unsigned int r;
  asm volatile("global_load_dword %0, %1, off sc0 sc1\n\ts_waitcnt vmcnt(0)"
               : "=v"(r) : "v"(p) : "memory");
  return r;
}
// tied 32-bit load: dest keeps CANARY until the load COMPLETES (safety net).
__device__ __forceinline__ void ld_sc01_rw(unsigned int* d, const unsigned int* p) {
  asm volatile("global_load_dword %0, %1, off sc0 sc1" : "+v"(*d) : "v"(p) : "memory");
}
__device__ __forceinline__ void ld_sc01_nw(unsigned int* d, const unsigned int* p) {
  asm volatile("global_load_dword %0, %1, off sc0 sc1" : "=v"(*d) : "v"(p) : "memory");
}
__device__ __forceinline__ void ld4_rawf(float4* d, const void* p) {
  asm volatile("global_load_dwordx4 %0, %1, off" : "=v"(*d) : "v"(p) : "memory");
}

// -------- one phase of the 4-group interleaved scan (phase k = 4t+G) --------
// Pipeline: publish p -> sweep ISSUE p+2 -> CHECK p+3 -> consume p+4.
// Buffers alternate by k&1 = G&1: BISS = sw[G&1], BCHK = sw[(G&1)^1].
// Uniform ledger (every tid<256 thread, every phase): 8 loads + 2 stores;
// check wait = vmcnt(12) = (k-1 stores:2) + (k loads:8) + (k stores:2).
// Waves 4-7: 2 x-issues/phase, stage waits vmcnt(2). hlast after check
// (over-waits only). Tied-canary regs catch any residual miscount -> re-poll.
#define PHASE(G, BISS, BCHK, XS0, XS1, XI0, XI1)                               \
  {                                                                            \
    if (tid < 256) {  /* sweep ISSUE: publish from phase k-2 */                \
      const int tp = ((G) >= 2) ? t : (t - 1);                                 \
      const unsigned int* sb =                                                 \
          ringc + ((((G) + 2) & 3) * 4 + (tp & 3)) * SLOTDW + tid;             \
      _Pragma("unroll")                                                        \
      for (int q = 0; q < 8; ++q) {                                            \
        BISS[q] = CANARY;                                                      \
        ld_sc01_rw(&BISS[q], sb + 256 * q);                                    \
      }                                                                        \
    } else {  /* x ISSUE for stage at k+1: group (G+2)&3 */                    \
      int t2 = t + (((G) >= 2) ? 1 : 0); if (t2 > 511) t2 = 511;               \
      const int u = tid & 255;                                                 \
      const float* px = x + ((size_t)t2 * 64 + b0 + 4 * (((G) + 2) & 3)        \
                             + (u >> 6)) * I_N + ((u & 63) << 3);              \
      ld4_rawf(&XI0, px); ld4_rawf(&XI1, px + 4);                              \
    }                                                                          \
    /* ---- MFMA over full 16-row panel; keep lane-group G's rows ---- */      \
    {                                                                          \
      f32x4 acc0 = {}, acc1 = {}, acc2 = {}, acc3 = {};                        \
      const int abase = (l & 15) * AP_STRIDE + wv * KW + ((l >> 4) << 3);      \
      _Pragma("unroll")                                                        \
      for (int kst = 0; kst < 6; ++kst) {                                      \
        bf16x8 a = *(const bf16x8*)(Apan + abase + kst * 32);                  \
        acc0 = __builtin_amdgcn_mfma_f32_16x16x32_bf16(a, Bh[kst][0], acc0, 0, 0, 0); \
        acc1 = __builtin_amdgcn_mfma_f32_16x16x32_bf16(a, Bh[kst][1], acc1, 0, 0, 0); \
        acc2 = __builtin_amdgcn_mfma_f32_16x16x32_bf16(a, Bh[kst][2], acc2, 0, 0, 0); \
        acc3 = __builtin_amdgcn_mfma_f32_16x16x32_bf16(a, Bh[kst][3], acc3, 0, 0, 0); \
      }                                                                        \
      if ((l >> 4) == (G)) {                                                   \
        float* rb = Rbuf + wv * 256 + (l & 15) * 4;                            \
        *(f32x4*)(rb +   0) = acc0; *(f32x4*)(rb +  64) = acc1;                \
        *(f32x4*)(rb + 128) = acc2; *(f32x4*)(rb + 192) = acc3;                \
      }                                                                        \
    }                                                                          \
    barrier_lds(); /* S1 */                                                    \
    if (tid < 256) {                                                           \
      float v = pbv;                                                           \
      _Pragma("unroll")                                                        \
      for (int kk = 0; kk < 8; ++kk) v += Rbuf[kk * 256 + tid];                \
      const float hval = tanhf(v);                                             \
      const unsigned int pk16 = f2bf(hval);                                    \
      const unsigned int oth = (unsigned int)__shfl_xor((int)pk16, 4);         \
      const unsigned int pk = (tid & 4) ? (oth | (pk16 << 16))                 \
                                        : (pk16 | (oth << 16));                \
      const int dwi = (tid & 3) * 512 + m * 32 + (tid >> 3);                   \
      if (!(tid & 4)) {  /* 2 stores: ring data + ring canary */               \
        st_sc01(ringc + ((G) * 4 + (t & 3)) * SLOTDW + dwi, pk);               \
        st_sc01(ringc + ((G) * 4 + ((t + 2) & 3)) * SLOTDW + dwi, CANARY);     \
      } else {           /* 2 stores: hs data + dup canary (same addr/val) */  \
        st_raw32((unsigned int*)hs +                                           \
                 ((size_t)t * 64 + b0 + 4 * (G) + (tid & 3)) * 512 +           \
                 m * 32 + (tid >> 3), pk);                                     \
        st_sc01(ringc + ((G) * 4 + ((t + 2) & 3)) * SLOTDW + dwi, CANARY);     \
      }                                                                        \
      asm volatile("s_waitcnt vmcnt(12)" ::: "memory");                        \
      __builtin_amdgcn_sched_barrier(0);                                       \
      if (!(t == 0 && (G) < 3)) {  /* CHECK buffer issued at k-1 */            \
        bool bad = false;                                                      \
        _Pragma("unroll")                                                      \
        for (int q = 0; q < 8; ++q) bad |= (BCHK[q] == CANARY);                \
        if (bad) {  /* straggler/miscount fallback: re-poll (always sound) */  \
          const int ts = ((G) == 3) ? t : (t - 1);                             \
          const unsigned int* sb2 =                                            \
              ringc + ((((G) + 1) & 3) * 4 + (ts & 3)) * SLOTDW + tid;         \
          int itc = 0;                                                         \
          do {                                                                 \
            _Pragma("unroll")                                                  \
            for (int q = 0; q < 8; ++q) ld_sc01_nw(&BCHK[q], sb2 + 256 * q);   \
            asm volatile("s_waitcnt vmcnt(0)" ::: "memory");                   \
            __builtin_amdgcn_sched_barrier(0);                                 \
            bad = false;                                                       \
            _Pragma("unroll")                                                  \
            for (int q = 0; q < 8; ++q) bad |= (BCHK[q] == CANARY);            \
          } while (bad && ++itc < POLL_CAP);                                   \
        }                                                                      \
        _Pragma("unroll")  /* stage into rows of group (G+1)&3 */              \
        for (int q = 0; q < 8; ++q)                                            \
          *(unsigned int*)(Apan + (4 * (((G) + 1) & 3) + (q >> 1)) * AP_STRIDE \
                           + ((tid + ((q & 1) << 8)) << 1)) = BCHK[q];         \
      }                                                                        \
      if (t == T_N - 1)  /* after check: only over-waits later ledgers */      \
        hlast[(size_t)(b0 + 4 * (G) + (tid & 3)) * H_N + cbh + (tid >> 2)] = hval; \
    } else {  /* x stage from buffer issued at k-1 */                          \
      asm volatile("s_waitcnt vmcnt(2)" ::: "memory");                         \
      __builtin_amdgcn_sched_barrier(0);                                       \
      const int u = tid & 255;                                                 \
      *(bf16x8*)(Apan + (4 * (((G) + 1) & 3) + (u >> 6)) * AP_STRIDE + H_N     \
                 + ((u & 63) << 3)) = cvt8v(XS0, XS1);                         \
    }                                                                          \
    barrier_lds(); /* S2 */                                                    \
  }

// 4-group interleaved persistent scan. Grid 64 = 4 clusters x 16 members,
// 512 thr (8 waves). Cluster c: batches [16c,16c+16); member m: h-cols
// [64m,64m+64). Writes hs (bf16 [T][64][H]) + hlast (fp32). FC separate.
__global__ __launch_bounds__(NTHR, 2) void rnn_scan(
    const float* __restrict__ x, const float* __restrict__ hidden,
    const float* __restrict__ Wih, const float* __restrict__ Whh,
    const float* __restrict__ bih, const float* __restrict__ bhh,
    unsigned short* __restrict__ hs, float* __restrict__ hlast,
    unsigned int* __restrict__ ring, unsigned int* __restrict__ flags)
{
  __shared__ __align__(16) unsigned short Apan[16 * AP_STRIDE];  // 49408 B
  __shared__ __align__(16) float Rbuf[8 * 256];                  //  8192 B
  __shared__ char pad_[24576];  // -> 82176 B total: strictly 1 block/CU

  const int tid = threadIdx.x;
  const int l = tid & 63, wv = tid >> 6;
  const int bid = blockIdx.x;
  const int c = bid & 3;
  const int m = bid >> 2;
  const int b0 = c * 16;
  const int cbh = m * COLS_H;
  unsigned int* ringc = ring + (size_t)c * 4 * 4 * SLOTDW;  // [4 grp][4 slot]
  unsigned int* bar = flags + c * 64;
  if (x == nullptr) pad_[0] = 1;  // keep the LDS pad alive (never true)

  // ---- persistent recurrence weights: K=1536 = [Whh | Wih], 64 cols ----
  bf16x8 Bh[6][4];
  {
    const int kb0 = wv * KW + ((l >> 4) << 3);
#pragma unroll
    for (int kst = 0; kst < 6; ++kst) {
      const int k = kb0 + kst * 32;
#pragma unroll
      for (int f = 0; f < 4; ++f) {
        const int col = cbh + f * 16 + (l & 15);
        const float* src = (k < H_N) ? (Whh + (size_t)col * H_N + k)
                                     : (Wih + (size_t)col * I_N + (k - H_N));
        Bh[kst][f] = cvt8f(src);
      }
    }
  }
  const int rcol = (tid < 256) ? (tid >> 2) : 0;
  const float pbv = bih[cbh + rcol] + bhh[cbh + rcol];

  // ---- stage hidden rows 0-15 ----
  {
    int q = tid;
#pragma unroll
    for (int i = 0; i < 4; ++i, q += NTHR) {
      const int row = q >> 7, col8 = (q & 127) << 3;
      *(bf16x8*)(Apan + row * AP_STRIDE + col8) =
          cvt8f(hidden + (size_t)(b0 + row) * H_N + col8);
    }
  }
  // ---- stage x_0 rows 0-15 ----
  {
    int q = tid;
#pragma unroll
    for (int i = 0; i < 2; ++i, q += NTHR) {
      const int row = q >> 6, col8 = (q & 63) << 3;
      *(bf16x8*)(Apan + row * AP_STRIDE + H_N + col8) =
          cvt8f(x + (size_t)(b0 + row) * I_N + col8);
    }
  }
  // ---- canary all 16 slot-regions (own 128 dwords per member) ----
  if (tid < 256 && !(tid & 4)) {
    const int dwi = (tid & 3) * 512 + m * 32 + (tid >> 3);
#pragma unroll
    for (int s = 0; s < 16; ++s) st_sc01(ringc + s * SLOTDW + dwi, CANARY);
  }
  asm volatile("s_waitcnt vmcnt(0)" ::: "memory");
  __syncthreads();
  // ---- member barrier (sc1 flags, capped) ----
  if (tid == 0) st_sc01(&bar[m], 1u);
  if (tid < NMEM) {
    int it = 0;
    while (ld_sc01(&bar[tid]) < 1u && ++it < HS_CAP)
      if (it > 64) __builtin_amdgcn_s_sleep(1);
  }
  // ---- preamble x issue: XA <- x^{G1}_0 (staged at phase 0) ----
  float4 XA0, XA1, XB0, XB1;
  if (wv >= 4) {
    const int u = tid & 255;
    const float* px = x + (size_t)(b0 + 4 + (u >> 6)) * I_N + ((u & 63) << 3);
    ld4_rawf(&XA0, px); ld4_rawf(&XA1, px + 4);
  }
  __syncthreads();  // preamble drain: phase-0 vmcnt ledgers start clean

  unsigned int sw0[8], sw1[8];
#pragma unroll
  for (int q = 0; q < 8; ++q) { sw0[q] = CANARY; sw1[q] = CANARY; }

  for (int t = 0; t < T_N; ++t) {
    PHASE(0, sw0, sw1, XA0, XA1, XB0, XB1)
    PHASE(1, sw1, sw0, XB0, XB1, XA0, XA1)
    PHASE(2, sw0, sw1, XA0, XA1, XB0, XB1)
    PHASE(3, sw1, sw0, XB0, XB1, XA0, XA1)
  }
}

// FC GEMM: C[m][n] = sum_k hs[m][k]*Wfcb[n][k] + bfc[n]; fp32 out.
__global__ __launch_bounds__(256) void gemm_fc(const unsigned short* __restrict__ A,
                                               const unsigned short* __restrict__ Bt,
                                               const float* __restrict__ bias,
                                               float* __restrict__ C) {
  const int N = O_N, K = H_N;
  const int bm = blockIdx.x >> 2, bn = blockIdx.x & 3;
  const int l = threadIdx.x & 63, w = threadIdx.x >> 6;
  const int wr = w >> 1, wc = w & 1;
  const int row_a = bm * 128 + wr * 64 + (l & 15);
  const int row_b = bn * 128 + wc * 64 + (l & 15);
  const int koff = (l >> 4) * 8;
  f32x4 acc[4][4] = {};
  for (int k = 0; k < K; k += 32) {
    bf16x8 a[4], b[4];
#pragma unroll
    for (int i = 0; i < 4; i++)
      a[i] = *(const bf16x8*)(A + (size_t)(row_a + i * 16) * K + k + koff);
#pragma unroll
    for (int i = 0; i < 4; i++)
      b[i] = *(const bf16x8*)(Bt + (size_t)(row_b + i * 16) * K + k + koff);
#pragma unroll
    for (int i = 0; i < 4; i++)
#pragma unroll
      for (int j = 0; j < 4; j++)
        acc[i][j] = __builtin_amdgcn_mfma_f32_16x16x32_bf16(a[i], b[j], acc[i][j], 0, 0, 0);
  }
  const int orow = bm * 128 + wr * 64 + ((l >> 4) << 2);
  const int ocol = bn * 128 + wc * 64 + (l & 15);
#pragma unroll
  for (int i = 0; i < 4; i++)
#pragma unroll
    for (int j = 0; j < 4; j++) {
      const int r0 = orow + i * 16, c0 = ocol + j * 16;
      const float bv = bias[c0];
#pragma unroll
      for (int r = 0; r < 4; r++)
        C[(size_t)(r0 + r) * N + c0] = acc[i][j][r] + bv;
    }
}

// fp32 -> bf16 convert (for Wfc)
__global__ __launch_bounds__(256) void cvt8(const float* __restrict__ s,
                                            unsigned short* __restrict__ d, long n) {
  long i = ((long)blockIdx.x * blockDim.x + threadIdx.x) * 8;
  if (i < n) *(bf16x8*)(d + i) = cvt8f(s + i);
}

extern "C" void kernel_launch(void* const* d_in, const int* in_sizes, int n_in,
                              void* d_out, int out_size, void* d_ws, size_t ws_size,
                              hipStream_t stream) {
  const float* x   = (const float*)d_in[0];
  const float* hid = (const float*)d_in[1];
  const float* Wih = (const float*)d_in[2];
  const float* Whh = (const float*)d_in[3];
  const float* bih = (const float*)d_in[4];
  const float* bhh = (const float*)d_in[5];
  const float* Wfc = (const float*)d_in[6];
  const float* bfc = (const float*)d_in[7];

  float* out   = (float*)d_out;                      // fp32 [T*B][O]
  float* hlast = out + (size_t)32768 * 512;          // fp32 [B][H]

  unsigned int*   flags = (unsigned int*)d_ws;                       // 4 KB
  unsigned int*   ring  = (unsigned int*)((char*)d_ws + 4096);       // 512 KB
  unsigned short* Wfcb  = (unsigned short*)((char*)d_ws + 4096 + 524288);  // 1 MB
  unsigned short* hsb   = Wfcb + (size_t)512 * 1024;                 // 67.1 MB

  (void)hipMemsetAsync(flags, 0, 4096, stream);
  cvt8<<<256, 256, 0, stream>>>(Wfc, Wfcb, (long)512 * 1024);
  rnn_scan<<<64, NTHR, 0, stream>>>(x, hid, Wih, Whh, bih, bhh, hsb, hlast, ring, flags);
  gemm_fc<<<1024, 256, 0, stream>>>(hsb, Wfcb, bfc, out);
}

// Round 16
// 2389.747 us; speedup vs baseline: 1.3051x; 1.1183x over previous
//
#include <hip/hip_runtime.h>

typedef __attribute__((ext_vector_type(8))) short bf16x8;
typedef __attribute__((ext_vector_type(4))) float f32x4;

#define T_N 512
#define I_N 512
#define H_N 1024
#define O_N 512
#define NCL 4            // clusters; c = bid&3; 16 batch rows each (2 groups x 8)
#define NMEM 16          // members; m = bid>>2; 64 h-cols, 32 out-cols each
#define NTHR 512
#define COLS_H 64
#define KW 192           // recurrence K-slice per wave (8*192 = 1536)
#define KWFC 128         // FC K-slice per wave (8*128 = 1024)
#define AP_STRIDE 1544   // A-panel row stride (1536 + 8 pad)
#define RST 9            // reduce-buffer stride
#define CANARY 0xFFFFFFFFu   // bf16 NaN pair; tanh output bits never match
#define HS_CAP 20000000
#define POLL_CAP 200000

__device__ __forceinline__ unsigned short f2bf(float f) {
  unsigned int u = __float_as_uint(f);
  u += 0x7fffu + ((u >> 16) & 1u);
  return (unsigned short)(u >> 16);
}
__device__ __forceinline__ bf16x8 cvt8f(const float* __restrict__ p) {
  float4 a = *(const float4*)p;
  float4 b = *(const float4*)(p + 4);
  bf16x8 r;
  r[0] = (short)f2bf(a.x); r[1] = (short)f2bf(a.y);
  r[2] = (short)f2bf(a.z); r[3] = (short)f2bf(a.w);
  r[4] = (short)f2bf(b.x); r[5] = (short)f2bf(b.y);
  r[6] = (short)f2bf(b.z); r[7] = (short)f2bf(b.w);
  return r;
}
__device__ __forceinline__ bf16x8 cvt8v(float4 a, float4 b) {
  bf16x8 r;
  r[0] = (short)f2bf(a.x); r[1] = (short)f2bf(a.y);
  r[2] = (short)f2bf(a.z); r[3] = (short)f2bf(a.w);
  r[4] = (short)f2bf(b.x); r[5] = (short)f2bf(b.y);
  r[6] = (short)f2bf(b.z); r[7] = (short)f2bf(b.w);
  return r;
}

// RAW workgroup barrier: orders LDS only; vmem stays IN FLIGHT across it.
__device__ __forceinline__ void barrier_lds() {
  asm volatile("s_waitcnt lgkmcnt(0)" ::: "memory");
  __builtin_amdgcn_s_barrier();
  __builtin_amdgcn_sched_barrier(0);
}

// memory-side coherent channel (bypass L1+L2) — the only HW-proven path
__device__ __forceinline__ void st_sc01(unsigned int* p, unsigned int v) {
  asm volatile("global_store_dword %0, %1, off sc0 sc1" :: "v"(p), "v"(v) : "memory");
}
__device__ __forceinline__ void st_raw32(unsigned int* p, unsigned int v) {
  asm volatile("global_store_dword %0, %1, off" :: "v"(p), "v"(v) : "memory");
}
__device__ __forceinline__ unsigned int ld_sc01(const unsigned int* p) {
  unsigned int r;
  asm volatile("global_load_dword %0, %1, off sc0 sc1\n\ts_waitcnt vmcnt(0)"
               : "=v"(r) : "v"(p) : "memory");
  return r;
}
// tied 32-bit load: dest keeps CANARY until the load COMPLETES (safety net).
__device__ __forceinline__ void ld_sc01_rw(unsigned int* d, const unsigned int* p) {
  asm volatile("global_load_dword %0, %1, off sc0 sc1" : "+v"(*d) : "v"(p) : "memory");
}
__device__ __forceinline__ void ld_sc01_nw(unsigned int* d, const unsigned int* p) {
  asm volatile("global_load_dword %0, %1, off sc0 sc1" : "=v"(*d) : "v"(p) : "memory");
}
__device__ __forceinline__ void ld4_rawf(float4* d, const void* p) {
  asm volatile("global_load_dwordx4 %0, %1, off" : "=v"(*d) : "v"(p) : "memory");
}

// -------- one phase of the 2-group interleaved scan, FC fused --------
// G = 0: rows 0-7 / 1: rows 8-15. Sweep loads issued FIRST (canary-pre-init),
// fly across the RAW barriers under MFMA+reduce+publish, checked with counted
// vmcnt. FC(t-1) for group G computed from Apan rows G (= h_G(t-1)) by all
// waves (K split 8-way), reduced by waves 0-3 in the transport-wait window.
// Ledger: waves 0-3 = 8 sweeps + {ring,canary,out} -> vmcnt(3) (t=0: 2 -> 2);
//         waves 4-7 = 8 sweeps + {2 x-prefetch} -> vmcnt(4) (tail: 0).
#define PHASE(G, X0, X1, X2, X3)                                               \
  {                                                                            \
    const bool doSweep = !((G) == 0 && t == 0);                                \
    unsigned int sw[8];                                                        \
    const unsigned int* spd = ringc;                                           \
    if (doSweep) {                                                             \
      const int swt = t - 1 + (G);                                             \
      spd = ringc + (((G) ^ 1) * 4 + (swt & 3)) * 4096 + tid;                  \
      _Pragma("unroll")                                                        \
      for (int j = 0; j < 8; ++j) {                                            \
        sw[j] = CANARY;                                                        \
        ld_sc01_rw(&sw[j], spd + 512 * j);                                     \
      }                                                                        \
    }                                                                          \
    /* ---- recurrence MFMA (reads Apan staged in earlier phases) ---- */      \
    {                                                                          \
      f32x4 acc0 = {}, acc1 = {}, acc2 = {}, acc3 = {};                        \
      const int abase = (l & 15) * AP_STRIDE + wv * KW + ((l >> 4) << 3);      \
      _Pragma("unroll")                                                        \
      for (int kst = 0; kst < 6; ++kst) {                                      \
        bf16x8 a = *(const bf16x8*)(Apan + abase + kst * 32);                  \
        acc0 = __builtin_amdgcn_mfma_f32_16x16x32_bf16(a, Bh[kst][0], acc0,0,0,0);\
        acc1 = __builtin_amdgcn_mfma_f32_16x16x32_bf16(a, Bh[kst][1], acc1,0,0,0);\
        acc2 = __builtin_amdgcn_mfma_f32_16x16x32_bf16(a, Bh[kst][2], acc2,0,0,0);\
        acc3 = __builtin_amdgcn_mfma_f32_16x16x32_bf16(a, Bh[kst][3], acc3,0,0,0);\
      }                                                                        \
      if ((l >> 5) == (G)) {  /* group G's output rows live in these lanes */  \
        const int rb = ((l >> 4) & 1) << 2;                                    \
        *(f32x4*)(R + (size_t)(wv * COLS_H +  0 + (l & 15)) * RST + rb) = acc0;\
        *(f32x4*)(R + (size_t)(wv * COLS_H + 16 + (l & 15)) * RST + rb) = acc1;\
        *(f32x4*)(R + (size_t)(wv * COLS_H + 32 + (l & 15)) * RST + rb) = acc2;\
        *(f32x4*)(R + (size_t)(wv * COLS_H + 48 + (l & 15)) * RST + rb) = acc3;\
      }                                                                        \
    }                                                                          \
    /* ---- FC MFMA: out(t-1) for group G from Apan rows G (h part only) */    \
    if (t > 0) {                                                               \
      f32x4 afc0 = {}, afc1 = {};                                              \
      const int ab2 = (l & 15) * AP_STRIDE + wv * KWFC + ((l >> 4) << 3);      \
      _Pragma("unroll")                                                        \
      for (int kst = 0; kst < 4; ++kst) {                                      \
        bf16x8 a = *(const bf16x8*)(Apan + ab2 + kst * 32);                    \
        afc0 = __builtin_amdgcn_mfma_f32_16x16x32_bf16(a, Bf[kst][0], afc0,0,0,0);\
        afc1 = __builtin_amdgcn_mfma_f32_16x16x32_bf16(a, Bf[kst][1], afc1,0,0,0);\
      }                                                                        \
      if ((l >> 5) == (G)) {                                                   \
        const int rb = ((l >> 4) & 1) << 2;                                    \
        *(f32x4*)(R2 + (size_t)(wv * 32 +      (l & 15)) * RST + rb) = afc0;   \
        *(f32x4*)(R2 + (size_t)(wv * 32 + 16 + (l & 15)) * RST + rb) = afc1;   \
      }                                                                        \
    }                                                                          \
    barrier_lds();  /* S1: LDS-only barrier; sweeps stay in flight */          \
    if (wv < 4) {                                                              \
      float v0 = pb0, v1 = pb1;                                                \
      _Pragma("unroll")                                                        \
      for (int kk = 0; kk < 8; ++kk) {                                         \
        v0 += R[(size_t)(kk * COLS_H + 2 * rcp)     * RST + rrow];             \
        v1 += R[(size_t)(kk * COLS_H + 2 * rcp + 1) * RST + rrow];             \
      }                                                                        \
      float vfc = bfv;                                                         \
      if (t > 0) {                                                             \
        _Pragma("unroll")                                                      \
        for (int kk = 0; kk < 8; ++kk)                                         \
          vfc += R2[(size_t)(kk * 32 + rcp) * RST + rrow];                     \
      }                                                                        \
      const float h0 = tanhf(v0), h1 = tanhf(v1);                              \
      const unsigned int pk =                                                  \
          (unsigned int)f2bf(h0) | ((unsigned int)f2bf(h1) << 16);             \
      /* stores asm-pinned AFTER the 8 sweep loads */                          \
      st_sc01(ringc + ((G) * 4 + (t & 3)) * 4096 + pubdw, pk);                 \
      st_sc01(ringc + ((G) * 4 + ((t + 2) & 3)) * 4096 + pubdw, CANARY);       \
      if (t > 0)                                                               \
        st_raw32((unsigned int*)out +                                          \
                 ((size_t)(t - 1) * 64 + b0 + (G) * 8 + rrow) * O_N            \
                 + cbfc + rcp, __float_as_uint(vfc));                          \
      if (doSweep) {                                                           \
        if (t > 0) asm volatile("s_waitcnt vmcnt(3)" ::: "memory");            \
        else       asm volatile("s_waitcnt vmcnt(2)" ::: "memory");            \
        __builtin_amdgcn_sched_barrier(0);                                     \
        bool bad = false;                                                      \
        _Pragma("unroll")                                                      \
        for (int j = 0; j < 8; ++j) bad |= (sw[j] == CANARY);                  \
        if (bad) {                                                             \
          int it = 0;                                                          \
          do {                                                                 \
            _Pragma("unroll")                                                  \
            for (int j = 0; j < 8; ++j) ld_sc01_nw(&sw[j], spd + 512 * j);     \
            asm volatile("s_waitcnt vmcnt(0)" ::: "memory");                   \
            __builtin_amdgcn_sched_barrier(0);                                 \
            bad = false;                                                       \
            _Pragma("unroll")                                                  \
            for (int j = 0; j < 8; ++j) bad |= (sw[j] == CANARY);              \
          } while (bad && ++it < POLL_CAP);                                    \
        }                                                                      \
      }                                                                        \
      if (t == T_N - 1) {                                                      \
        float2 fv; fv.x = h0; fv.y = h1;                                       \
        *(float2*)(hlast + (size_t)(b0 + (G) * 8 + rrow) * H_N + cbh + 2 * rcp) = fv; \
      }                                                                        \
    } else {                                                                   \
      if (t + 1 < T_N) {  /* stage x^G_{t+1}; regs retired by prev vmcnt */    \
        const int u = tid & 255;                                               \
        *(bf16x8*)(Apan + ((G) * 8 + (u >> 6)) * AP_STRIDE + H_N + ((u & 63) << 3)) = \
            cvt8v(X0, X1);                                                     \
        *(bf16x8*)(Apan + ((G) * 8 + (u >> 6) + 4) * AP_STRIDE + H_N + ((u & 63) << 3)) = \
            cvt8v(X2, X3);                                                     \
      }                                                                        \
      int nIss = 0;                                                            \
      if (t + 2 < T_N) {  /* prefetch x^G_{t+2} */                             \
        const int u = tid & 255;                                               \
        const float* px = x + ((size_t)(t + 2) * 64 + b0 + (G) * 8 + (u >> 6)) * I_N \
                          + ((u & 63) << 3);                                   \
        ld4_rawf(&X0, px); ld4_rawf(&X1, px + 4);                              \
        ld4_rawf(&X2, px + 4 * I_N); ld4_rawf(&X3, px + 4 * I_N + 4);          \
        nIss = 4;                                                              \
      }                                                                        \
      if (doSweep) {                                                           \
        if (nIss) asm volatile("s_waitcnt vmcnt(4)" ::: "memory");             \
        else      asm volatile("s_waitcnt vmcnt(0)" ::: "memory");             \
        __builtin_amdgcn_sched_barrier(0);                                     \
        bool bad = false;                                                      \
        _Pragma("unroll")                                                      \
        for (int j = 0; j < 8; ++j) bad |= (sw[j] == CANARY);                  \
        if (bad) {                                                             \
          int it = 0;                                                          \
          do {                                                                 \
            _Pragma("unroll")                                                  \
            for (int j = 0; j < 8; ++j) ld_sc01_nw(&sw[j], spd + 512 * j);     \
            asm volatile("s_waitcnt vmcnt(0)" ::: "memory");                   \
            __builtin_amdgcn_sched_barrier(0);                                 \
            bad = false;                                                       \
            _Pragma("unroll")                                                  \
            for (int j = 0; j < 8; ++j) bad |= (sw[j] == CANARY);              \
          } while (bad && ++it < POLL_CAP);                                    \
        }                                                                      \
      }                                                                        \
    }                                                                          \
    if (doSweep) {  /* stage swept h (row j, dword-col tid) for next MFMA */   \
      _Pragma("unroll")                                                        \
      for (int j = 0; j < 8; ++j)                                              \
        *(unsigned int*)(Apan + ((((G) ^ 1) * 8) + j) * AP_STRIDE + (tid << 1)) = sw[j]; \
    }                                                                          \
    barrier_lds();  /* S2: LDS-only barrier */                                 \
  }

// Fully-fused interleaved persistent scan (recurrence + FC). Grid 64 =
// 4 clusters x 16 members, 512 thr. Cluster c: batches [16c,16c+16) as
// groups A=[+0,+8) B=[+8,+16). Member m: h-cols [64m,64m+64), out-cols
// [32m,32m+32). Writes out (fp32 [T*B][O]) + hlast (fp32). One dispatch.
__global__ __launch_bounds__(NTHR, 2) void rnn_fused(
    const float* __restrict__ x, const float* __restrict__ hidden,
    const float* __restrict__ Wih, const float* __restrict__ Whh,
    const float* __restrict__ bih, const float* __restrict__ bhh,
    const float* __restrict__ Wfc, const float* __restrict__ bfc,
    float* __restrict__ out, float* __restrict__ hlast,
    unsigned int* __restrict__ ring, unsigned int* __restrict__ flags)
{
  __shared__ __align__(16) unsigned short Apan[16 * AP_STRIDE];  // 49408 B
  __shared__ __align__(16) float R [8 * COLS_H * RST];           // 18432 B
  __shared__ __align__(16) float R2[8 * 32 * RST];               //  9216 B

  const int tid = threadIdx.x;
  const int l = tid & 63, wv = tid >> 6;
  const int bid = blockIdx.x;
  const int c = bid & 3;
  const int m = bid >> 2;
  const int b0 = c * 16;
  const int cbh = m * COLS_H;
  const int cbfc = m * 32;
  unsigned int* ringc = ring + (size_t)c * 2 * 4 * 4096;  // [2 grp][4 slot][4096 dw]
  unsigned int* bar = flags + c * 64;

  // ---- persistent recurrence weights: K=1536 = [Whh | Wih], 64 cols ----
  bf16x8 Bh[6][4];
  {
    const int kb0 = wv * KW + ((l >> 4) << 3);
#pragma unroll
    for (int kst = 0; kst < 6; ++kst) {
      const int k = kb0 + kst * 32;
#pragma unroll
      for (int f = 0; f < 4; ++f) {
        const int col = cbh + f * 16 + (l & 15);
        const float* src = (k < H_N) ? (Whh + (size_t)col * H_N + k)
                                     : (Wih + (size_t)col * I_N + (k - H_N));
        Bh[kst][f] = cvt8f(src);
      }
    }
  }
  // ---- persistent FC weights: K=1024, 32 out-cols ----
  bf16x8 Bf[4][2];
  {
    const int kb0 = wv * KWFC + ((l >> 4) << 3);
#pragma unroll
    for (int kst = 0; kst < 4; ++kst)
#pragma unroll
      for (int f = 0; f < 2; ++f)
        Bf[kst][f] = cvt8f(Wfc + (size_t)(cbfc + f * 16 + (l & 15)) * H_N + kb0 + kst * 32);
  }
  const int rrow = (tid >> 5) & 7;
  const int rcp  = tid & 31;
  const float pb0 = bih[cbh + 2 * rcp]     + bhh[cbh + 2 * rcp];
  const float pb1 = bih[cbh + 2 * rcp + 1] + bhh[cbh + 2 * rcp + 1];
  const float bfv = bfc[cbfc + rcp];
  const int pubdw = rrow * 512 + m * 32 + rcp;

  // ---- stage hidden rows 0-15 (both groups) ----
  {
    int q = tid;
#pragma unroll
    for (int i = 0; i < 4; ++i, q += NTHR) {
      const int row = q >> 7, col8 = (q & 127) << 3;
      *(bf16x8*)(Apan + row * AP_STRIDE + col8) =
          cvt8f(hidden + (size_t)(b0 + row) * H_N + col8);
    }
  }
  // ---- stage x_0 rows 0-15 ----
  {
    int q = tid;
#pragma unroll
    for (int i = 0; i < 2; ++i, q += NTHR) {
      const int row = q >> 6, col8 = (q & 63) << 3;
      *(bf16x8*)(Apan + row * AP_STRIDE + H_N + col8) =
          cvt8f(x + (size_t)(b0 + row) * I_N + col8);
    }
  }
  // ---- canary all 4 slots of both rings (own columns) ----
  if (tid < 256) {
#pragma unroll
    for (int s = 0; s < 8; ++s) st_sc01(ringc + s * 4096 + pubdw, CANARY);
  }
  asm volatile("s_waitcnt vmcnt(0)" ::: "memory");
  __syncthreads();
  // ---- member barrier (sc1 flags, capped) ----
  if (tid == 0) st_sc01(&bar[m], 1u);
  if (tid < NMEM) {
    int it = 0;
    while (ld_sc01(&bar[tid]) < 1u && ++it < HS_CAP)
      if (it > 64) __builtin_amdgcn_s_sleep(1);
  }
  // ---- prefetch x_1 for both groups (waves 4-7) ----
  float4 xA0, xA1, xA2, xA3, xB0, xB1, xB2, xB3;
  if (wv >= 4) {
    const int u = tid & 255;
    const float* pa = x + (size_t)(64 + b0 + (u >> 6)) * I_N + ((u & 63) << 3);
    ld4_rawf(&xA0, pa); ld4_rawf(&xA1, pa + 4);
    ld4_rawf(&xA2, pa + 4 * I_N); ld4_rawf(&xA3, pa + 4 * I_N + 4);
    const float* pb = x + (size_t)(64 + b0 + 8 + (u >> 6)) * I_N + ((u & 63) << 3);
    ld4_rawf(&xB0, pb); ld4_rawf(&xB1, pb + 4);
    ld4_rawf(&xB2, pb + 4 * I_N); ld4_rawf(&xB3, pb + 4 * I_N + 4);
  }
  __syncthreads();  // preamble drain (plain) — t=0 vmcnt ledgers start clean

  for (int t = 0; t < T_N; ++t) {
    PHASE(0, xA0, xA1, xA2, xA3)   // group A step t
    PHASE(1, xB0, xB1, xB2, xB3)   // group B step t
  }

  // ================= tail: FC for t = 511, both groups =================
  // After [B,511]: rows 0-7 = h_A(511) (staged in-loop). Re-poll h_B(511).
  {
    const unsigned int* sp = ringc + (1 * 4 + (511 & 3)) * 4096 + tid;
    unsigned int sw[8];
    int it = 0; bool bad;
    do {
#pragma unroll
      for (int j = 0; j < 8; ++j) ld_sc01_nw(&sw[j], sp + 512 * j);
      asm volatile("s_waitcnt vmcnt(0)" ::: "memory");
      __builtin_amdgcn_sched_barrier(0);
      bad = false;
#pragma unroll
      for (int j = 0; j < 8; ++j) bad |= (sw[j] == CANARY);
    } while (bad && ++it < POLL_CAP);
#pragma unroll
    for (int j = 0; j < 8; ++j)
      *(unsigned int*)(Apan + (8 + j) * AP_STRIDE + (tid << 1)) = sw[j];
  }
  __syncthreads();
  {
    f32x4 afc0 = {}, afc1 = {};
    const int ab2 = (l & 15) * AP_STRIDE + wv * KWFC + ((l >> 4) << 3);
#pragma unroll
    for (int kst = 0; kst < 4; ++kst) {
      bf16x8 a = *(const bf16x8*)(Apan + ab2 + kst * 32);
      afc0 = __builtin_amdgcn_mfma_f32_16x16x32_bf16(a, Bf[kst][0], afc0, 0, 0, 0);
      afc1 = __builtin_amdgcn_mfma_f32_16x16x32_bf16(a, Bf[kst][1], afc1, 0, 0, 0);
    }
#pragma unroll
    for (int g = 0; g < 2; ++g) {
      if ((l >> 5) == g) {
        const int rb = ((l >> 4) & 1) << 2;
        *(f32x4*)(R2 + (size_t)(wv * 32 +      (l & 15)) * RST + rb) = afc0;
        *(f32x4*)(R2 + (size_t)(wv * 32 + 16 + (l & 15)) * RST + rb) = afc1;
      }
      __syncthreads();
      if (tid < 256) {
        float vfc = bfv;
#pragma unroll
        for (int kk = 0; kk < 8; ++kk)
          vfc += R2[(size_t)(kk * 32 + rcp) * RST + rrow];
        out[((size_t)511 * 64 + b0 + g * 8 + rrow) * O_N + cbfc + rcp] = vfc;
      }
      __syncthreads();
    }
  }
}

extern "C" void kernel_launch(void* const* d_in, const int* in_sizes, int n_in,
                              void* d_out, int out_size, void* d_ws, size_t ws_size,
                              hipStream_t stream) {
  const float* x   = (const float*)d_in[0];
  const float* hid = (const float*)d_in[1];
  const float* Wih = (const float*)d_in[2];
  const float* Whh = (const float*)d_in[3];
  const float* bih = (const float*)d_in[4];
  const float* bhh = (const float*)d_in[5];
  const float* Wfc = (const float*)d_in[6];
  const float* bfc = (const float*)d_in[7];

  float* out   = (float*)d_out;                      // fp32 [T*B][O]
  float* hlast = out + (size_t)32768 * 512;          // fp32 [B][H]

  unsigned int* flags = (unsigned int*)d_ws;                  // 4 KB
  unsigned int* ring  = (unsigned int*)((char*)d_ws + 4096);  // 512 KB

  (void)hipMemsetAsync(flags, 0, 4096, stream);
  rnn_fused<<<64, NTHR, 0, stream>>>(x, hid, Wih, Whh, bih, bhh, Wfc, bfc,
                                     out, hlast, ring, flags);
}

// Round 17
// 1633.581 us; speedup vs baseline: 1.9093x; 1.4629x over previous
//
#include <hip/hip_runtime.h>

typedef __attribute__((ext_vector_type(8))) short bf16x8;
typedef __attribute__((ext_vector_type(4))) float f32x4;

#define T_N 512
#define I_N 512
#define H_N 1024
#define O_N 512
#define NCL 4            // clusters; c = bid&3; 16 batch rows each (2 groups x 8)
#define NMEM 16          // members; m = bid>>2; 64 h-cols each
#define NTHR 512
#define COLS_H 64
#define KW 192           // recurrence K-slice per wave (8*192 = 1536)
#define AP_STRIDE 1544   // A-panel row stride (1536 + 8 pad)
#define RST 9            // reduce-buffer stride
#define CANARY 0xFFFFFFFFu   // bf16 NaN pair; tanh output bits never match
#define HS_CAP 20000000
#define POLL_CAP 200000

__device__ __forceinline__ unsigned short f2bf(float f) {
  unsigned int u = __float_as_uint(f);
  u += 0x7fffu + ((u >> 16) & 1u);
  return (unsigned short)(u >> 16);
}
__device__ __forceinline__ bf16x8 cvt8f(const float* __restrict__ p) {
  float4 a = *(const float4*)p;
  float4 b = *(const float4*)(p + 4);
  bf16x8 r;
  r[0] = (short)f2bf(a.x); r[1] = (short)f2bf(a.y);
  r[2] = (short)f2bf(a.z); r[3] = (short)f2bf(a.w);
  r[4] = (short)f2bf(b.x); r[5] = (short)f2bf(b.y);
  r[6] = (short)f2bf(b.z); r[7] = (short)f2bf(b.w);
  return r;
}
__device__ __forceinline__ bf16x8 cvt8v(float4 a, float4 b) {
  bf16x8 r;
  r[0] = (short)f2bf(a.x); r[1] = (short)f2bf(a.y);
  r[2] = (short)f2bf(a.z); r[3] = (short)f2bf(a.w);
  r[4] = (short)f2bf(b.x); r[5] = (short)f2bf(b.y);
  r[6] = (short)f2bf(b.z); r[7] = (short)f2bf(b.w);
  return r;
}

// RAW workgroup barrier: orders LDS only; vmem (sweeps/publishes/prefetches)
// stays IN FLIGHT across it. __syncthreads would emit s_waitcnt vmcnt(0) and
// drain the pipelined sweep loads (the R11 stall).
__device__ __forceinline__ void barrier_lds() {
  asm volatile("s_waitcnt lgkmcnt(0)" ::: "memory");
  __builtin_amdgcn_s_barrier();
  __builtin_amdgcn_sched_barrier(0);
}

// memory-side coherent channel (bypass L1+L2) — the only HW-proven path (R4/R7/R9)
__device__ __forceinline__ void st_sc01(unsigned int* p, unsigned int v) {
  asm volatile("global_store_dword %0, %1, off sc0 sc1" :: "v"(p), "v"(v) : "memory");
}
__device__ __forceinline__ void st_raw32(unsigned int* p, unsigned int v) {
  asm volatile("global_store_dword %0, %1, off" :: "v"(p), "v"(v) : "memory");
}
__device__ __forceinline__ unsigned int ld_sc01(const unsigned int* p) {
  unsigned int r;
  asm volatile("global_load_dword %0, %1, off sc0 sc1\n\ts_waitcnt vmcnt(0)"
               : "=v"(r) : "v"(p) : "memory");
  return r;
}
// tied 32-bit load: dest keeps its pre-init (CANARY) until the load COMPLETES.
// Safety net: any vmcnt miscount -> check sees CANARY -> re-poll loop.
__device__ __forceinline__ void ld_sc01_rw(unsigned int* d, const unsigned int* p) {
  asm volatile("global_load_dword %0, %1, off sc0 sc1" : "+v"(*d) : "v"(p) : "memory");
}
__device__ __forceinline__ void ld_sc01_nw(unsigned int* d, const unsigned int* p) {
  asm volatile("global_load_dword %0, %1, off sc0 sc1" : "=v"(*d) : "v"(p) : "memory");
}
__device__ __forceinline__ void ld4_rawf(float4* d, const void* p) {
  asm volatile("global_load_dwordx4 %0, %1, off" : "=v"(*d) : "v"(p) : "memory");
}

// One phase of the 2-way interleaved scan (G = 0: rows 0-7 / 1: rows 8-15).
// 8 coalesced sweep loads issued FIRST (canary-pre-init), fly across the RAW
// barriers under MFMA+reduce+publish, checked with counted vmcnt at phase end.
// vmcnt ledger (no implicit drains anywhere in the loop):
//   waves 0-3: [8 sweep][3 stores] -> check vmcnt(3)
//   waves 4-7: [8 sweep][2 x-prefetch] -> check vmcnt(4) (vmcnt(0) at tail);
//              x regs staged this phase were retired by the PREVIOUS phase's
//              counted check (everything older than its newest retires in-order).
#define PHASE(G, X0, X1, X2, X3)                                               \
  {                                                                            \
    const bool doSweep = !((G) == 0 && t == 0) && !((G) == 1 && t == T_N - 1); \
    unsigned int sw[8];                                                        \
    const unsigned int* spd = ringc;                                           \
    if (doSweep) {                                                             \
      const int swt = t - 1 + (G);                                             \
      spd = ringc + (((G) ^ 1) * 4 + (swt & 3)) * 4096 + tid;                  \
      _Pragma("unroll")                                                        \
      for (int j = 0; j < 8; ++j) {                                            \
        sw[j] = CANARY;                                                        \
        ld_sc01_rw(&sw[j], spd + 512 * j);                                     \
      }                                                                        \
    }                                                                          \
    /* ---- MFMA (reads Apan staged in earlier phases) ---- */                 \
    f32x4 acc0 = {}, acc1 = {}, acc2 = {}, acc3 = {};                          \
    const int abase = (l & 15) * AP_STRIDE + wv * KW + ((l >> 4) << 3);        \
    _Pragma("unroll")                                                          \
    for (int kst = 0; kst < 6; ++kst) {                                        \
      bf16x8 a = *(const bf16x8*)(Apan + abase + kst * 32);                    \
      acc0 = __builtin_amdgcn_mfma_f32_16x16x32_bf16(a, Bh[kst][0], acc0,0,0,0);\
      acc1 = __builtin_amdgcn_mfma_f32_16x16x32_bf16(a, Bh[kst][1], acc1,0,0,0);\
      acc2 = __builtin_amdgcn_mfma_f32_16x16x32_bf16(a, Bh[kst][2], acc2,0,0,0);\
      acc3 = __builtin_amdgcn_mfma_f32_16x16x32_bf16(a, Bh[kst][3], acc3,0,0,0);\
    }                                                                          \
    if ((l >> 5) == (G)) {  /* group G's output rows live in these lanes */    \
      const int rb = ((l >> 4) & 1) << 2;                                      \
      *(f32x4*)(R + (size_t)(wv * COLS_H +  0 + (l & 15)) * RST + rb) = acc0;  \
      *(f32x4*)(R + (size_t)(wv * COLS_H + 16 + (l & 15)) * RST + rb) = acc1;  \
      *(f32x4*)(R + (size_t)(wv * COLS_H + 32 + (l & 15)) * RST + rb) = acc2;  \
      *(f32x4*)(R + (size_t)(wv * COLS_H + 48 + (l & 15)) * RST + rb) = acc3;  \
    }                                                                          \
    barrier_lds();  /* S1: LDS-only barrier; sweeps stay in flight */          \
    if (wv < 4) {                                                              \
      float v0 = pb0, v1 = pb1;                                                \
      _Pragma("unroll")                                                        \
      for (int kk = 0; kk < 8; ++kk) {                                         \
        v0 += R[(size_t)(kk * COLS_H + 2 * rcp)     * RST + rrow];             \
        v1 += R[(size_t)(kk * COLS_H + 2 * rcp + 1) * RST + rrow];             \
      }                                                                        \
      const float h0 = tanhf(v0), h1 = tanhf(v1);                              \
      const unsigned int pk =                                                  \
          (unsigned int)f2bf(h0) | ((unsigned int)f2bf(h1) << 16);             \
      /* 3 stores, asm-pinned AFTER the 8 sweep loads */                       \
      st_sc01(ringc + ((G) * 4 + (t & 3)) * 4096 + pubdw, pk);                 \
      st_sc01(ringc + ((G) * 4 + ((t + 2) & 3)) * 4096 + pubdw, CANARY);       \
      st_raw32((unsigned int*)(hs + ((size_t)t * 64 + b0 + (G) * 8 + rrow) * H_N \
                               + cbh + 2 * rcp), pk);                          \
      if (doSweep) {                                                           \
        asm volatile("s_waitcnt vmcnt(3)" ::: "memory");                       \
        __builtin_amdgcn_sched_barrier(0);                                     \
        bool bad = false;                                                      \
        _Pragma("unroll")                                                      \
        for (int j = 0; j < 8; ++j) bad |= (sw[j] == CANARY);                  \
        if (bad) {                                                             \
          int it = 0;                                                          \
          do {                                                                 \
            _Pragma("unroll")                                                  \
            for (int j = 0; j < 8; ++j) ld_sc01_nw(&sw[j], spd + 512 * j);     \
            asm volatile("s_waitcnt vmcnt(0)" ::: "memory");                   \
            __builtin_amdgcn_sched_barrier(0);                                 \
            bad = false;                                                       \
            _Pragma("unroll")                                                  \
            for (int j = 0; j < 8; ++j) bad |= (sw[j] == CANARY);              \
          } while (bad && ++it < POLL_CAP);                                    \
        }                                                                      \
      }                                                                        \
      if (t == T_N - 1) {                                                      \
        float2 fv; fv.x = h0; fv.y = h1;                                       \
        *(float2*)(hlast + (size_t)(b0 + (G) * 8 + rrow) * H_N + cbh + 2 * rcp) = fv; \
      }                                                                        \
    } else {                                                                   \
      if (t + 1 < T_N) {  /* stage x^G_{t+1}; regs retired by prev vmcnt */    \
        const int u = tid & 255;                                               \
        *(bf16x8*)(Apan + ((G) * 8 + (u >> 6)) * AP_STRIDE + H_N + ((u & 63) << 3)) = \
            cvt8v(X0, X1);                                                     \
        *(bf16x8*)(Apan + ((G) * 8 + (u >> 6) + 4) * AP_STRIDE + H_N + ((u & 63) << 3)) = \
            cvt8v(X2, X3);                                                     \
      }                                                                        \
      int nIss = 0;                                                            \
      if (t + 2 < T_N) {  /* prefetch x^G_{t+2} */                             \
        const int u = tid & 255;                                               \
        const float* px = x + ((size_t)(t + 2) * 64 + b0 + (G) * 8 + (u >> 6)) * I_N \
                          + ((u & 63) << 3);                                   \
        ld4_rawf(&X0, px); ld4_rawf(&X1, px + 4);                              \
        ld4_rawf(&X2, px + 4 * I_N); ld4_rawf(&X3, px + 4 * I_N + 4);          \
        nIss = 4;                                                              \
      }                                                                        \
      if (doSweep) {                                                           \
        if (nIss) asm volatile("s_waitcnt vmcnt(4)" ::: "memory");             \
        else      asm volatile("s_waitcnt vmcnt(0)" ::: "memory");             \
        __builtin_amdgcn_sched_barrier(0);                                     \
        bool bad = false;                                                      \
        _Pragma("unroll")                                                      \
        for (int j = 0; j < 8; ++j) bad |= (sw[j] == CANARY);                  \
        if (bad) {                                                             \
          int it = 0;                                                          \
          do {                                                                 \
            _Pragma("unroll")                                                  \
            for (int j = 0; j < 8; ++j) ld_sc01_nw(&sw[j], spd + 512 * j);     \
            asm volatile("s_waitcnt vmcnt(0)" ::: "memory");                   \
            __builtin_amdgcn_sched_barrier(0);                                 \
            bad = false;                                                       \
            _Pragma("unroll")                                                  \
            for (int j = 0; j < 8; ++j) bad |= (sw[j] == CANARY);              \
          } while (bad && ++it < POLL_CAP);                                    \
        }                                                                      \
      }                                                                        \
    }                                                                          \
    if (doSweep) {  /* stage swept h (row j, dword-col tid) for next MFMA */   \
      _Pragma("unroll")                                                        \
      for (int j = 0; j < 8; ++j)                                              \
        *(unsigned int*)(Apan + ((((G) ^ 1) * 8) + j) * AP_STRIDE + (tid << 1)) = sw[j]; \
    }                                                                          \
    barrier_lds();  /* S2: LDS-only barrier */                                 \
  }

// Interleaved persistent scan. Grid 64 = 4 clusters x 16 members, 512 thr.
// Cluster c: batches [16c,16c+16) as groups A=[+0,+8) B=[+8,+16).
// Writes hs (bf16, [T][64][H]) and hlast (fp32). FC done by gemm_fc after.
__global__ __launch_bounds__(NTHR, 2) void rnn_scan(
    const float* __restrict__ x, const float* __restrict__ hidden,
    const float* __restrict__ Wih, const float* __restrict__ Whh,
    const float* __restrict__ bih, const float* __restrict__ bhh,
    unsigned short* __restrict__ hs, float* __restrict__ hlast,
    unsigned int* __restrict__ ring, unsigned int* __restrict__ flags)
{
  __shared__ __align__(16) unsigned short Apan[16 * AP_STRIDE];  // 49408 B
  __shared__ __align__(16) float R[8 * COLS_H * RST];            // 18432 B

  const int tid = threadIdx.x;
  const int l = tid & 63, wv = tid >> 6;
  const int bid = blockIdx.x;
  const int c = bid & 3;
  const int m = bid >> 2;
  const int b0 = c * 16;
  const int cbh = m * COLS_H;
  unsigned int* ringc = ring + (size_t)c * 2 * 4 * 4096;  // [2 grp][4 slot][4096 dw]
  unsigned int* bar = flags + c * 64;

  // ---- persistent recurrence weights: K=1536 = [Whh | Wih], 64 cols ----
  bf16x8 Bh[6][4];
  {
    const int kb0 = wv * KW + ((l >> 4) << 3);
#pragma unroll
    for (int kst = 0; kst < 6; ++kst) {
      const int k = kb0 + kst * 32;
#pragma unroll
      for (int f = 0; f < 4; ++f) {
        const int col = cbh + f * 16 + (l & 15);
        const float* src = (k < H_N) ? (Whh + (size_t)col * H_N + k)
                                     : (Wih + (size_t)col * I_N + (k - H_N));
        Bh[kst][f] = cvt8f(src);
      }
    }
  }
  const int rrow = (tid >> 5) & 7;
  const int rcp  = tid & 31;
  const float pb0 = bih[cbh + 2 * rcp]     + bhh[cbh + 2 * rcp];
  const float pb1 = bih[cbh + 2 * rcp + 1] + bhh[cbh + 2 * rcp + 1];
  const int pubdw = rrow * 512 + m * 32 + rcp;

  // ---- stage hidden rows 0-15 (both groups) ----
  {
    int q = tid;
#pragma unroll
    for (int i = 0; i < 4; ++i, q += NTHR) {
      const int row = q >> 7, col8 = (q & 127) << 3;
      *(bf16x8*)(Apan + row * AP_STRIDE + col8) =
          cvt8f(hidden + (size_t)(b0 + row) * H_N + col8);
    }
  }
  // ---- stage x_0 rows 0-15 ----
  {
    int q = tid;
#pragma unroll
    for (int i = 0; i < 2; ++i, q += NTHR) {
      const int row = q >> 6, col8 = (q & 63) << 3;
      *(bf16x8*)(Apan + row * AP_STRIDE + H_N + col8) =
          cvt8f(x + (size_t)(b0 + row) * I_N + col8);
    }
  }
  // ---- canary all 4 slots of both rings (own columns) ----
  if (tid < 256) {
#pragma unroll
    for (int s = 0; s < 8; ++s) st_sc01(ringc + s * 4096 + pubdw, CANARY);
  }
  asm volatile("s_waitcnt vmcnt(0)" ::: "memory");
  __syncthreads();
  // ---- member barrier (sc1 flags, capped) ----
  if (tid == 0) st_sc01(&bar[m], 1u);
  if (tid < NMEM) {
    int it = 0;
    while (ld_sc01(&bar[tid]) < 1u && ++it < HS_CAP)
      if (it > 64) __builtin_amdgcn_s_sleep(1);
  }
  // ---- prefetch x_1 for both groups (waves 4-7): xA(4) then xB(4) ----
  float4 xA0, xA1, xA2, xA3, xB0, xB1, xB2, xB3;
  if (wv >= 4) {
    const int u = tid & 255;
    const float* pa = x + (size_t)(64 + b0 + (u >> 6)) * I_N + ((u & 63) << 3);
    ld4_rawf(&xA0, pa); ld4_rawf(&xA1, pa + 4);
    ld4_rawf(&xA2, pa + 4 * I_N); ld4_rawf(&xA3, pa + 4 * I_N + 4);
    const float* pb = x + (size_t)(64 + b0 + 8 + (u >> 6)) * I_N + ((u & 63) << 3);
    ld4_rawf(&xB0, pb); ld4_rawf(&xB1, pb + 4);
    ld4_rawf(&xB2, pb + 4 * I_N); ld4_rawf(&xB3, pb + 4 * I_N + 4);
  }
  __syncthreads();  // preamble drain (plain) — makes t=0 vmcnt ledger trivial

  for (int t = 0; t < T_N; ++t) {
    PHASE(0, xA0, xA1, xA2, xA3)   // group A step t
    PHASE(1, xB0, xB1, xB2, xB3)   // group B step t
  }
}

// FC GEMM: C[m][n] = sum_k hs[m][k]*Wfcb[n][k] + bfc[n]; fp32 out.
// M=32768, N=512, K=1024. 128x128 block tile, 4 waves, 64x64 wave tiles.
__global__ __launch_bounds__(256) void gemm_fc(const unsigned short* __restrict__ A,
                                               const unsigned short* __restrict__ Bt,
                                               const float* __restrict__ bias,
                                               float* __restrict__ C) {
  const int N = O_N, K = H_N;
  const int bm = blockIdx.x >> 2, bn = blockIdx.x & 3;
  const int l = threadIdx.x & 63, w = threadIdx.x >> 6;
  const int wr = w >> 1, wc = w & 1;
  const int row_a = bm * 128 + wr * 64 + (l & 15);
  const int row_b = bn * 128 + wc * 64 + (l & 15);
  const int koff = (l >> 4) * 8;
  f32x4 acc[4][4] = {};
  for (int k = 0; k < K; k += 32) {
    bf16x8 a[4], b[4];
#pragma unroll
    for (int i = 0; i < 4; i++)
      a[i] = *(const bf16x8*)(A + (size_t)(row_a + i * 16) * K + k + koff);
#pragma unroll
    for (int i = 0; i < 4; i++)
      b[i] = *(const bf16x8*)(Bt + (size_t)(row_b + i * 16) * K + k + koff);
#pragma unroll
    for (int i = 0; i < 4; i++)
#pragma unroll
      for (int j = 0; j < 4; j++)
        acc[i][j] = __builtin_amdgcn_mfma_f32_16x16x32_bf16(a[i], b[j], acc[i][j], 0, 0, 0);
  }
  const int orow = bm * 128 + wr * 64 + ((l >> 4) << 2);
  const int ocol = bn * 128 + wc * 64 + (l & 15);
#pragma unroll
  for (int i = 0; i < 4; i++)
#pragma unroll
    for (int j = 0; j < 4; j++) {
      const int r0 = orow + i * 16, c0 = ocol + j * 16;
      const float bv = bias[c0];
#pragma unroll
      for (int r = 0; r < 4; r++)
        C[(size_t)(r0 + r) * N + c0] = acc[i][j][r] + bv;
    }
}

// fp32 -> bf16 convert (for Wfc)
__global__ __launch_bounds__(256) void cvt8(const float* __restrict__ s,
                                            unsigned short* __restrict__ d, long n) {
  long i = ((long)blockIdx.x * blockDim.x + threadIdx.x) * 8;
  if (i < n) *(bf16x8*)(d + i) = cvt8f(s + i);
}

extern "C" void kernel_launch(void* const* d_in, const int* in_sizes, int n_in,
                              void* d_out, int out_size, void* d_ws, size_t ws_size,
                              hipStream_t stream) {
  const float* x   = (const float*)d_in[0];
  const float* hid = (const float*)d_in[1];
  const float* Wih = (const float*)d_in[2];
  const float* Whh = (const float*)d_in[3];
  const float* bih = (const float*)d_in[4];
  const float* bhh = (const float*)d_in[5];
  const float* Wfc = (const float*)d_in[6];
  const float* bfc = (const float*)d_in[7];

  float* out   = (float*)d_out;                      // fp32 [T*B][O]
  float* hlast = out + (size_t)32768 * 512;          // fp32 [B][H]

  unsigned int*   flags = (unsigned int*)d_ws;                       // 4 KB
  unsigned int*   ring  = (unsigned int*)((char*)d_ws + 4096);       // 512 KB
  unsigned short* Wfcb  = (unsigned short*)((char*)d_ws + 4096 + 524288);  // 1 MB
  unsigned short* hsb   = Wfcb + (size_t)512 * 1024;                 // 67.1 MB

  (void)hipMemsetAsync(flags, 0, 4096, stream);
  cvt8<<<256, 256, 0, stream>>>(Wfc, Wfcb, (long)512 * 1024);
  rnn_scan<<<64, NTHR, 0, stream>>>(x, hid, Wih, Whh, bih, bhh, hsb, hlast, ring, flags);
  gemm_fc<<<1024, 256, 0, stream>>>(hsb, Wfcb, bfc, out);
}